// Round 22
// baseline (145.233 us; speedup 1.0000x reference)
//
#include <hip/hip_runtime.h>
#include <stdint.h>
#include <stddef.h>

#define B_ 2
#define T_ 2048
#define D_ 1024
#define H_ 16
#define U_ 64
#define M_ (B_ * T_)   // 4096
#define N_ (H_ * U_)   // 1024

typedef __attribute__((ext_vector_type(4))) float f32x4;
typedef __attribute__((ext_vector_type(8))) short s16x8;
typedef __attribute__((ext_vector_type(8))) __bf16 b16x8;

static_assert(sizeof(s16x8) == 16, "frag size");

__device__ __forceinline__ unsigned short f2bf(float f) {
  unsigned int u = __float_as_uint(f);
  u += 0x7FFFu + ((u >> 16) & 1u);     // RNE
  return (unsigned short)(u >> 16);
}

// --- bare-metal v_exp_f32 (D = 2^S0)
__device__ __forceinline__ float exp2_hw(float x) {
  float r;
  asm("v_exp_f32 %0, %1" : "=v"(r) : "v"(x));
  return r;
}
// --- packed f32x2 -> bf16x2 (RNE), single instruction
__device__ __forceinline__ unsigned int cvtpk_bf16(float lo, float hi) {
  unsigned int r;
  asm("v_cvt_pk_bf16_f32 %0, %1, %2" : "=v"(r) : "v"(lo), "v"(hi));
  return r;
}

// --- MFMA wrapper: SFINAE hedge — works whether the builtin takes short8 or bf16x8
template <typename V>
__device__ __forceinline__ auto mfma16_impl(V a, V b, f32x4 c, int)
    -> decltype(__builtin_amdgcn_mfma_f32_16x16x32_bf16(a, b, c, 0, 0, 0)) {
  return __builtin_amdgcn_mfma_f32_16x16x32_bf16(a, b, c, 0, 0, 0);
}
template <typename V>
__device__ __forceinline__ f32x4 mfma16_impl(V a, V b, f32x4 c, long) {
  return __builtin_amdgcn_mfma_f32_16x16x32_bf16(
      __builtin_bit_cast(b16x8, a), __builtin_bit_cast(b16x8, b), c, 0, 0, 0);
}
__device__ __forceinline__ f32x4 mfma16(s16x8 a, s16x8 b, f32x4 c) {
  return mfma16_impl(a, b, c, 0);
}

// --- async global->LDS, 16B per lane (m97 lever)
__device__ __forceinline__ void gld16(const unsigned short* g, unsigned short* l) {
  __builtin_amdgcn_global_load_lds(
      (const __attribute__((address_space(1))) void*)g,
      (__attribute__((address_space(3))) void*)l, 16, 0, 0);
}

// ---------------------------------------------------------------- K0: merged prep (v2)
__global__ void prep_kernel(const float* __restrict__ x, const int* __restrict__ mask,
                            const float* __restrict__ w0, const float* __restrict__ w1,
                            const float* __restrict__ w2, const float* __restrict__ w3,
                            unsigned short* __restrict__ o0, unsigned short* __restrict__ o1,
                            unsigned short* __restrict__ o2, unsigned short* __restrict__ o3,
                            unsigned short* __restrict__ xb) {
  const int tid = threadIdx.x;
  if (blockIdx.x < 1024) {
    __shared__ float tile[64][68];   // 68-f stride: 16B-aligned float4 rows
    const int id = blockIdx.x;
    const int mz = id >> 8, by = (id >> 4) & 15, bx = id & 15;
    const float* w;
    unsigned short* o;
    switch (mz) {
      case 0: w = w0; o = o0; break;
      case 1: w = w1; o = o1; break;
      case 2: w = w2; o = o2; break;
      default: w = w3; o = o3; break;
    }
    const int kb = by * 64, nb = bx * 64;
    const int r = tid >> 4, c4 = (tid & 15) * 4;
#pragma unroll
    for (int i = 0; i < 4; i++)
      *(float4*)&tile[r + i * 16][c4] =
          *(const float4*)(w + (size_t)(kb + r + i * 16) * 1024 + nb + c4);
    __syncthreads();
#pragma unroll
    for (int i = 0; i < 2; i++) {
      const int idx = tid + i * 256;
      const int n = idx >> 3;           // 0..63
      const int k0 = (idx & 7) * 8;     // 0..56
      unsigned int u0 = cvtpk_bf16(tile[k0 + 0][n], tile[k0 + 1][n]);
      unsigned int u1 = cvtpk_bf16(tile[k0 + 2][n], tile[k0 + 3][n]);
      unsigned int u2 = cvtpk_bf16(tile[k0 + 4][n], tile[k0 + 5][n]);
      unsigned int u3 = cvtpk_bf16(tile[k0 + 6][n], tile[k0 + 7][n]);
      uint4 o4 = {u0, u1, u2, u3};
      *(uint4*)(o + (size_t)(nb + n) * 1024 + kb + k0) = o4;
    }
  } else {
    const int idx = ((blockIdx.x - 1024) * 256 + tid) * 4;  // 4 elems/thread
    const int row = idx >> 10;                              // b*T + t
    const float m = (float)mask[row];
    float4 v = *(const float4*)(x + idx);
    ushort4 o;
    o.x = f2bf(v.x * m);
    o.y = f2bf(v.y * m);
    o.z = f2bf(v.z * m);
    o.w = f2bf(v.w * m);
    *(ushort4*)(xb + idx) = o;
  }
}

// ---------------------------------------------------------------- GEMM 128x128 (BK=64+swz)
template <int MODE>
__device__ __forceinline__ void gemm64_body(const unsigned short* __restrict__ A,
                                            const unsigned short* __restrict__ Bt,
                                            void* __restrict__ Cout) {
  constexpr int Kd = 1024, Nd = 1024;
  __shared__ unsigned short la[128 * 64];  // [row][64k], swizzled contents, 16KB
  __shared__ unsigned short lb[128 * 64];
  const int tid = threadIdx.x;
  const int lane = tid & 63;
  const int w = tid >> 6;
  const int mb = blockIdx.y * 128, nb = blockIdx.x * 128;
  const int wm = (w >> 1) * 64, wn = (w & 1) * 64;
  const int lr = lane & 15, lg = lane >> 4;
  const int srow = tid >> 3;               // 0..31 (+i*32 per issue)
  const int scol = (tid & 7) * 8;
  const int sc = scol ^ ((srow & 7) << 3); // pre-swizzled SOURCE col
  const unsigned short* gA = A + (size_t)(mb + srow) * Kd + sc;
  const unsigned short* gB = Bt + (size_t)(nb + srow) * Kd + sc;
  unsigned short* lA = la + srow * 64 + scol;
  unsigned short* lB = lb + srow * 64 + scol;
  const int rsw = (lr & 7) << 3;           // read-side swizzle (shorts)

  f32x4 acc[4][4] = {};

  for (int kt = 0; kt < Kd; kt += 64) {
#pragma unroll
    for (int i = 0; i < 4; i++) {
      gld16(gA + kt + (size_t)(i * 32) * Kd, lA + i * 32 * 64);
      gld16(gB + kt + (size_t)(i * 32) * Kd, lB + i * 32 * 64);
    }
    __syncthreads();
#pragma unroll
    for (int ks = 0; ks < 2; ks++) {
      const int kc = (ks * 32 + lg * 8) ^ rsw;
      s16x8 af[4], bfr[4];
#pragma unroll
      for (int i = 0; i < 4; i++)
        af[i] = *(const s16x8*)(la + (wm + i * 16 + lr) * 64 + kc);
#pragma unroll
      for (int j = 0; j < 4; j++)
        bfr[j] = *(const s16x8*)(lb + (wn + j * 16 + lr) * 64 + kc);
#pragma unroll
      for (int i = 0; i < 4; i++)
#pragma unroll
        for (int j = 0; j < 4; j++)
          acc[i][j] = mfma16(af[i], bfr[j], acc[i][j]);
    }
    __syncthreads();
  }

#pragma unroll
  for (int i = 0; i < 4; i++)
#pragma unroll
    for (int j = 0; j < 4; j++) {
      const int col = nb + wn + j * 16 + lr;
      const int rowb = mb + wm + i * 16 + lg * 4;
      if (MODE == 0) {
        unsigned short* C = (unsigned short*)Cout;
#pragma unroll
        for (int r = 0; r < 4; r++) C[(size_t)(rowb + r) * Nd + col] = f2bf(acc[i][j][r]);
      } else {
        unsigned short* C = (unsigned short*)Cout;
        const size_t vrow = ((size_t)(rowb >> 11) * 16 + (col >> 6)) * 64 + (col & 63);
        ushort4 o;
#pragma unroll
        for (int r = 0; r < 4; r++) ((unsigned short*)&o)[r] = f2bf(acc[i][j][r]);
        *(ushort4*)(C + vrow * T_ + (rowb & 2047)) = o;
      }
    }
}

__global__ __launch_bounds__(256) void gemm_qkv(const unsigned short* __restrict__ A,
                                                const unsigned short* __restrict__ wq,
                                                const unsigned short* __restrict__ wk,
                                                const unsigned short* __restrict__ wv,
                                                unsigned short* __restrict__ cq,
                                                unsigned short* __restrict__ ck,
                                                unsigned short* __restrict__ vt) {
  if (blockIdx.z == 0) {
    gemm64_body<0>(A, wq, cq);
  } else if (blockIdx.z == 1) {
    gemm64_body<0>(A, wk, ck);
  } else {
    gemm64_body<2>(A, wv, vt);  // writes V directly transposed
  }
}

// ---------------------------------------------------------------- gemm_out: 128x64 tile
__global__ __launch_bounds__(256) void gemm_out(const unsigned short* __restrict__ A,
                                                const unsigned short* __restrict__ woT,
                                                float* __restrict__ C) {
  constexpr int Kd = 1024, Nd = 1024;
  __shared__ unsigned short la[128 * 64];  // A tile 128x64k, 16KB
  __shared__ unsigned short lb[64 * 64];   // B tile 64x64k, 8KB
  const int tid = threadIdx.x;
  const int lane = tid & 63;
  const int w = tid >> 6;
  const int mb = blockIdx.y * 128, nb = blockIdx.x * 64;
  const int wm = w * 32;                   // wave's 32 M-rows
  const int lr = lane & 15, lg = lane >> 4;
  const int srow = tid >> 3;               // 0..31
  const int scol = (tid & 7) * 8;
  const int sc = scol ^ ((srow & 7) << 3);
  const unsigned short* gA = A + (size_t)(mb + srow) * Kd + sc;
  const unsigned short* gB = woT + (size_t)(nb + srow) * Kd + sc;
  unsigned short* lA = la + srow * 64 + scol;
  unsigned short* lB = lb + srow * 64 + scol;
  const int rsw = (lr & 7) << 3;

  f32x4 acc[2][4] = {};

  for (int kt = 0; kt < Kd; kt += 64) {
#pragma unroll
    for (int i = 0; i < 4; i++)
      gld16(gA + kt + (size_t)(i * 32) * Kd, lA + i * 32 * 64);
#pragma unroll
    for (int i = 0; i < 2; i++)
      gld16(gB + kt + (size_t)(i * 32) * Kd, lB + i * 32 * 64);
    __syncthreads();
#pragma unroll
    for (int ks = 0; ks < 2; ks++) {
      const int kc = (ks * 32 + lg * 8) ^ rsw;
      s16x8 af[2], bfr[4];
#pragma unroll
      for (int i = 0; i < 2; i++)
        af[i] = *(const s16x8*)(la + (wm + i * 16 + lr) * 64 + kc);
#pragma unroll
      for (int j = 0; j < 4; j++)
        bfr[j] = *(const s16x8*)(lb + (j * 16 + lr) * 64 + kc);
#pragma unroll
      for (int i = 0; i < 2; i++)
#pragma unroll
        for (int j = 0; j < 4; j++)
          acc[i][j] = mfma16(af[i], bfr[j], acc[i][j]);
    }
    __syncthreads();
  }

#pragma unroll
  for (int i = 0; i < 2; i++)
#pragma unroll
    for (int j = 0; j < 4; j++) {
      const int col = nb + j * 16 + lr;
      const int rowb = mb + wm + i * 16 + lg * 4;
#pragma unroll
      for (int r = 0; r < 4; r++) C[(size_t)(rowb + r) * Nd + col] = acc[i][j][r];
    }
}

// ---------------------------------------------------------------- K3: flash attention v19
// attn17 body + J-PARITY SPLIT across 2 waves per block (grid 1024 x 128 threads =
// 2048 waves = 2 waves/SIMD — the regime attn13 showed interleaves ~free).
// Wave w processes tiles t == w (mod 2) of each pair-member chain (<=17 tiles vs 33),
// then an exact flash-combine per q-group through LDS (R8-verified math).
__global__ __launch_bounds__(128) void attn19_kernel(const unsigned short* __restrict__ Q,
                                                     const unsigned short* __restrict__ K,
                                                     const unsigned short* __restrict__ Vt,
                                                     const int* __restrict__ mask,
                                                     unsigned short* __restrict__ att) {
  __shared__ unsigned short pbuf[2][32 * 64];  // per-wave P repack, XOR-swizzled
  __shared__ float cb[36 * 64];                // combine buffer, element-major
  const int tid = threadIdx.x;
  const int w = tid >> 6, lane = tid & 63;
  const int li = lane & 15, lg = lane >> 4;
  const int bh = blockIdx.x & 31;
  const int b = bh >> 4, h = bh & 15;
  const int pr = blockIdx.x >> 5;           // 0..31: pair index

  const float CS = 0.125f * 1.44269504089f;   // 1/sqrt(U) * log2(e)
  const float PB = 10000.0f * 1.44269504089f; // pad bias, log2 domain
  const float THR = 8.0f;                     // defer-max threshold (log2 domain)

  const unsigned short* Kb = K + (size_t)(b * T_) * 1024 + h * 64;
  const unsigned short* Vtb = Vt + (size_t)bh * 64 * T_;
  const int* mk = mask + b * T_;

  const int xr = (li & 3) << 5;
  char* pbb = (char*)&pbuf[w][0];

  for (int g = 0; g < 2; g++) {
    const int qg = g == 0 ? (63 - pr) : pr;
    const int q0 = qg * 32;

    s16x8 qf[2][2];
#pragma unroll
    for (int f = 0; f < 2; f++) {
      const unsigned short* qrow = Q + ((size_t)(b * T_) + q0 + f * 16 + li) * 1024 + h * 64;
      qf[f][0] = *(const s16x8*)(qrow + lg * 8);
      qf[f][1] = *(const s16x8*)(qrow + 32 + lg * 8);
    }

    const int iq0 = q0 + li, iq1 = q0 + 16 + li;

    float mrun[2] = {-1e30f, -1e30f};
    f32x4 lp[2] = {};              // vectorized per-lane partial row-sums
    f32x4 acc[4][2] = {};          // [ufrag][ifrag]
    s16x8 vf[4][2];                // V fragments, consumed within each phase

    const int ntiles = (q0 + 95) >> 6;      // ceil((q0+32)/64)
    const int nmy = (ntiles - w + 1) >> 1;  // my tiles: t = w, w+2, ...

    auto loadK = [&](s16x8 (&dst)[4][2], int jb) {
#pragma unroll
      for (int jf = 0; jf < 4; jf++) {
        const unsigned short* kr = Kb + (size_t)(jb + jf * 16 + li) * 1024 + lg * 8;
        dst[jf][0] = *(const s16x8*)kr;
        dst[jf][1] = *(const s16x8*)(kr + 32);
      }
    };
    auto loadM = [&](int4 (&dst)[4], int jb) {
#pragma unroll
      for (int jf = 0; jf < 4; jf++)
        dst[jf] = *(const int4*)(mk + jb + jf * 16 + lg * 4);
    };
    auto loadV = [&](int jb) {
#pragma unroll
      for (int uf = 0; uf < 4; uf++) {
        const unsigned short* vr = Vtb + (size_t)(uf * 16 + li) * T_ + jb + lg * 8;
        vf[uf][0] = *(const s16x8*)vr;
        vf[uf][1] = *(const s16x8*)(vr + 32);
      }
    };
    auto qk = [&](f32x4 (&s)[4][2], s16x8 (&kc)[4][2]) {
      __builtin_amdgcn_s_setprio(1);
#pragma unroll
      for (int jf = 0; jf < 4; jf++) {
        f32x4 z = {};
        s[jf][0] = mfma16(kc[jf][0], qf[0][0], z);
        s[jf][0] = mfma16(kc[jf][1], qf[0][1], s[jf][0]);
        f32x4 z2 = {};
        s[jf][1] = mfma16(kc[jf][0], qf[1][0], z2);
        s[jf][1] = mfma16(kc[jf][1], qf[1][1], s[jf][1]);
      }
      __builtin_amdgcn_s_setprio(0);
    };
    auto smw = [&](f32x4 (&s)[4][2], int4 (&mv)[4], int jb) {
      const bool diag = (jb + 64 > q0);  // wave-uniform
      const int band = (mv[0].x & mv[0].y & mv[0].z & mv[0].w) &
                       (mv[1].x & mv[1].y & mv[1].z & mv[1].w) &
                       (mv[2].x & mv[2].y & mv[2].z & mv[2].w) &
                       (mv[3].x & mv[3].y & mv[3].z & mv[3].w);
      const bool noBias = __all(band != 0);
#pragma unroll
      for (int f = 0; f < 2; f++) {
        const int iq = f ? iq1 : iq0;
        f32x4 pv4 = {-3e38f, -3e38f, -3e38f, -3e38f};
        if (noBias) {
#pragma unroll
          for (int jf = 0; jf < 4; jf++) {
            f32x4 zz = s[jf][f] * CS;
            if (diag) {
#pragma unroll
              for (int r = 0; r < 4; r++)
                if (jb + jf * 16 + lg * 4 + r > iq) zz[r] = -1e30f;
            }
            s[jf][f] = zz;
            pv4 = __builtin_elementwise_max(pv4, zz);
          }
        } else {
#pragma unroll
          for (int jf = 0; jf < 4; jf++) {
            f32x4 zz;
#pragma unroll
            for (int r = 0; r < 4; r++) {
              float z = fmaf(s[jf][f][r], CS, ((&mv[jf].x)[r] ? 0.f : -PB));
              if (diag && (jb + jf * 16 + lg * 4 + r > iq)) z = -1e30f;
              zz[r] = z;
            }
            s[jf][f] = zz;
            pv4 = __builtin_elementwise_max(pv4, zz);
          }
        }
        const float pmax = fmaxf(fmaxf(pv4[0], pv4[1]), fmaxf(pv4[2], pv4[3]));
        if (!__all(pmax <= mrun[f] + THR)) {  // defer-max: rare after tile 0
          float rmax = fmaxf(pmax, __shfl_xor(pmax, 16));
          rmax = fmaxf(rmax, __shfl_xor(rmax, 32));
          const float mnew = fmaxf(mrun[f], rmax);
          const float al = exp2_hw(mrun[f] - mnew);
          lp[f] *= al;
#pragma unroll
          for (int uf = 0; uf < 4; uf++) acc[uf][f] *= al;
          mrun[f] = mnew;
        }
        const float mm = mrun[f];
#pragma unroll
        for (int jf = 0; jf < 4; jf++) {
          f32x4 p;
#pragma unroll
          for (int r = 0; r < 4; r++) p[r] = exp2_hw(s[jf][f][r] - mm);  // bounded 2^THR
          lp[f] += p;
          uint2 w2;
          w2.x = cvtpk_bf16(p[0], p[1]);
          w2.y = cvtpk_bf16(p[2], p[3]);
          const int wb = (((f * 16 + li) * 64 + jf * 16 + lg * 4) * 2) ^ xr;
          *(uint2*)(pbb + wb) = w2;
        }
      }
    };
    auto pv = [&]() {
      s16x8 pfrag[2][2];
#pragma unroll
      for (int f = 0; f < 2; f++)
#pragma unroll
        for (int hh = 0; hh < 2; hh++) {
          const int rd = (((f * 16 + li) * 64 + hh * 32 + lg * 8) * 2) ^ xr;
          pfrag[f][hh] = *(const s16x8*)(pbb + rd);
        }
      __builtin_amdgcn_s_setprio(1);
#pragma unroll
      for (int uf = 0; uf < 4; uf++)
#pragma unroll
        for (int f = 0; f < 2; f++) {
          acc[uf][f] = mfma16(vf[uf][0], pfrag[f][0], acc[uf][f]);
          acc[uf][f] = mfma16(vf[uf][1], pfrag[f][1], acc[uf][f]);
        }
      __builtin_amdgcn_s_setprio(0);
    };

    s16x8 kA[4][2], kB[4][2];
    f32x4 sA[4][2], sB[4][2];
    int4 mA[4], mB[4];

    // my tile i has jb = (w + 2*i)*64
    if (nmy > 0) {
      loadK(kA, w * 64);
      loadM(mA, w * 64);
      qk(sA, kA);
      if (nmy > 1) {
        loadK(kB, (w + 2) * 64);
        loadM(mB, (w + 2) * 64);
      }
      int i = 0;
      while (true) {
        // ---- phase A: my tile i (scores sA, mask mA; kB = K(i+1); kA dead)
        {
          const int jb = (w + 2 * i) * 64;
          loadV(jb);
          smw(sA, mA, jb);
          if (i + 1 < nmy) qk(sB, kB);
          if (i + 2 < nmy) {
            loadK(kA, (w + 2 * (i + 2)) * 64);
            loadM(mA, (w + 2 * (i + 2)) * 64);
          }
          pv();
        }
        if (i + 1 >= nmy) break;
        // ---- phase B: my tile i+1 (roles swapped)
        {
          const int jb = (w + 2 * (i + 1)) * 64;
          loadV(jb);
          smw(sB, mB, jb);
          if (i + 2 < nmy) qk(sA, kA);
          if (i + 3 < nmy) {
            loadK(kB, (w + 2 * (i + 3)) * 64);
            loadM(mB, (w + 2 * (i + 3)) * 64);
          }
          pv();
        }
        i += 2;
        if (i >= nmy) break;
      }
    }

    // ---- flash-combine of the two waves' partial states (exact; R8-verified math)
    // reduce lp across the 4 lanes of each row first
    float lred[2];
#pragma unroll
    for (int f = 0; f < 2; f++) {
      float l = (lp[f][0] + lp[f][1]) + (lp[f][2] + lp[f][3]);
      l += __shfl_xor(l, 16);
      l += __shfl_xor(l, 32);
      lred[f] = l;
    }
    if (w == 1) {
#pragma unroll
      for (int f = 0; f < 2; f++)
#pragma unroll
        for (int uf = 0; uf < 4; uf++)
#pragma unroll
          for (int r = 0; r < 4; r++)
            cb[(f * 16 + uf * 4 + r) * 64 + lane] = acc[uf][f][r];
      cb[32 * 64 + lane] = mrun[0];
      cb[33 * 64 + lane] = mrun[1];
      cb[34 * 64 + lane] = lred[0];
      cb[35 * 64 + lane] = lred[1];
    }
    __syncthreads();
    if (w == 0) {
#pragma unroll
      for (int f = 0; f < 2; f++) {
        const float mB2 = cb[(32 + f) * 64 + lane];
        const float lB2 = cb[(34 + f) * 64 + lane];
        const float m = fmaxf(mrun[f], mB2);
        const float aA = exp2_hw(mrun[f] - m);
        const float aB = exp2_hw(mB2 - m);
        const float inv = 1.0f / (aA * lred[f] + aB * lB2);
        unsigned short* arow = att + ((size_t)(b * T_) + q0 + f * 16 + li) * 1024 + h * 64;
#pragma unroll
        for (int uf = 0; uf < 4; uf++) {
          ushort4 o;
#pragma unroll
          for (int r = 0; r < 4; r++) {
            const float vB = cb[(f * 16 + uf * 4 + r) * 64 + lane];
            const float v = (aA * acc[uf][f][r] + aB * vB) * inv;
            ((unsigned short*)&o)[r] = __builtin_bit_cast(unsigned short, (__bf16)v);
          }
          *(ushort4*)(arow + uf * 16 + lg * 4) = o;
        }
      }
    }
    __syncthreads();  // cb reused next g
  }
}

// ----------------------------------------------------------------
extern "C" void kernel_launch(void* const* d_in, const int* in_sizes, int n_in,
                              void* d_out, int out_size, void* d_ws, size_t ws_size,
                              hipStream_t stream) {
  const float* x = (const float*)d_in[0];
  const int* mask = (const int*)d_in[1];
  const float* Wq = (const float*)d_in[2];
  const float* Wk = (const float*)d_in[3];
  const float* Wv = (const float*)d_in[4];
  const float* Wo = (const float*)d_in[5];

  const size_t MB = 1u << 20;
  char* ws = (char*)d_ws;
  unsigned short* wqT = (unsigned short*)(ws + 0 * MB);
  unsigned short* wkT = (unsigned short*)(ws + 2 * MB);
  unsigned short* wvT = (unsigned short*)(ws + 4 * MB);
  unsigned short* woT = (unsigned short*)(ws + 6 * MB);
  unsigned short* xb  = (unsigned short*)(ws + 8 * MB);   // 8MB; dead after gemm_qkv
  unsigned short* qb  = (unsigned short*)(ws + 16 * MB);  // 8MB
  unsigned short* kb  = (unsigned short*)(ws + 24 * MB);  // 8MB
  unsigned short* vt  = (unsigned short*)(ws + 32 * MB);  // 8MB, written transposed by gemm_qkv
  unsigned short* att = xb;                               // reuse xb slot (dead by attn time)
  (void)ws_size; (void)in_sizes; (void)n_in; (void)out_size;

  prep_kernel<<<dim3(5120), 256, 0, stream>>>(x, mask, Wq, Wk, Wv, Wo,
                                              wqT, wkT, wvT, woT, xb);
  gemm_qkv<<<dim3(8, 32, 3), 256, 0, stream>>>(xb, wqT, wkT, wvT, qb, kb, vt);
  attn19_kernel<<<dim3(1024), 128, 0, stream>>>(qb, kb, vt, mask, att);
  gemm_out<<<dim3(16, 32), 256, 0, stream>>>(att, woT, (float*)d_out);
}

// Round 23
// 137.153 us; speedup vs baseline: 1.0589x; 1.0589x over previous
//
#include <hip/hip_runtime.h>
#include <stdint.h>
#include <stddef.h>

#define B_ 2
#define T_ 2048
#define D_ 1024
#define H_ 16
#define U_ 64
#define M_ (B_ * T_)   // 4096
#define N_ (H_ * U_)   // 1024

typedef __attribute__((ext_vector_type(4))) float f32x4;
typedef __attribute__((ext_vector_type(8))) short s16x8;
typedef __attribute__((ext_vector_type(8))) __bf16 b16x8;

static_assert(sizeof(s16x8) == 16, "frag size");

__device__ __forceinline__ unsigned short f2bf(float f) {
  unsigned int u = __float_as_uint(f);
  u += 0x7FFFu + ((u >> 16) & 1u);     // RNE
  return (unsigned short)(u >> 16);
}

// --- bare-metal v_exp_f32 (D = 2^S0)
__device__ __forceinline__ float exp2_hw(float x) {
  float r;
  asm("v_exp_f32 %0, %1" : "=v"(r) : "v"(x));
  return r;
}
// --- packed f32x2 -> bf16x2 (RNE), single instruction
__device__ __forceinline__ unsigned int cvtpk_bf16(float lo, float hi) {
  unsigned int r;
  asm("v_cvt_pk_bf16_f32 %0, %1, %2" : "=v"(r) : "v"(lo), "v"(hi));
  return r;
}

// --- MFMA wrapper: SFINAE hedge — works whether the builtin takes short8 or bf16x8
template <typename V>
__device__ __forceinline__ auto mfma16_impl(V a, V b, f32x4 c, int)
    -> decltype(__builtin_amdgcn_mfma_f32_16x16x32_bf16(a, b, c, 0, 0, 0)) {
  return __builtin_amdgcn_mfma_f32_16x16x32_bf16(a, b, c, 0, 0, 0);
}
template <typename V>
__device__ __forceinline__ f32x4 mfma16_impl(V a, V b, f32x4 c, long) {
  return __builtin_amdgcn_mfma_f32_16x16x32_bf16(
      __builtin_bit_cast(b16x8, a), __builtin_bit_cast(b16x8, b), c, 0, 0, 0);
}
__device__ __forceinline__ f32x4 mfma16(s16x8 a, s16x8 b, f32x4 c) {
  return mfma16_impl(a, b, c, 0);
}

// --- async global->LDS, 16B per lane (m97 lever)
__device__ __forceinline__ void gld16(const unsigned short* g, unsigned short* l) {
  __builtin_amdgcn_global_load_lds(
      (const __attribute__((address_space(1))) void*)g,
      (__attribute__((address_space(3))) void*)l, 16, 0, 0);
}

// ---------------------------------------------------------------- K0: merged prep (v2)
// blocks [0,1024): W -> W^T bf16, VECTORIZED (float4 loads, ushort8 stores via cvt_pk)
// blocks [1024,5120): xb = bf16(x * mask), 1024 elems per block
__global__ void prep_kernel(const float* __restrict__ x, const int* __restrict__ mask,
                            const float* __restrict__ w0, const float* __restrict__ w1,
                            const float* __restrict__ w2, const float* __restrict__ w3,
                            unsigned short* __restrict__ o0, unsigned short* __restrict__ o1,
                            unsigned short* __restrict__ o2, unsigned short* __restrict__ o3,
                            unsigned short* __restrict__ xb) {
  const int tid = threadIdx.x;
  if (blockIdx.x < 1024) {
    __shared__ float tile[64][68];   // 68-f stride: 16B-aligned float4 rows
    const int id = blockIdx.x;
    const int mz = id >> 8, by = (id >> 4) & 15, bx = id & 15;
    const float* w;
    unsigned short* o;
    switch (mz) {
      case 0: w = w0; o = o0; break;
      case 1: w = w1; o = o1; break;
      case 2: w = w2; o = o2; break;
      default: w = w3; o = o3; break;
    }
    const int kb = by * 64, nb = bx * 64;
    const int r = tid >> 4, c4 = (tid & 15) * 4;
#pragma unroll
    for (int i = 0; i < 4; i++)
      *(float4*)&tile[r + i * 16][c4] =
          *(const float4*)(w + (size_t)(kb + r + i * 16) * 1024 + nb + c4);
    __syncthreads();
    // output: o[n][k] = bf16(w[k][n]); each thread emits 2x ushort8 (16B, contiguous k)
#pragma unroll
    for (int i = 0; i < 2; i++) {
      const int idx = tid + i * 256;
      const int n = idx >> 3;           // 0..63
      const int k0 = (idx & 7) * 8;     // 0..56
      unsigned int u0 = cvtpk_bf16(tile[k0 + 0][n], tile[k0 + 1][n]);
      unsigned int u1 = cvtpk_bf16(tile[k0 + 2][n], tile[k0 + 3][n]);
      unsigned int u2 = cvtpk_bf16(tile[k0 + 4][n], tile[k0 + 5][n]);
      unsigned int u3 = cvtpk_bf16(tile[k0 + 6][n], tile[k0 + 7][n]);
      uint4 o4 = {u0, u1, u2, u3};
      *(uint4*)(o + (size_t)(nb + n) * 1024 + kb + k0) = o4;
    }
  } else {
    const int idx = ((blockIdx.x - 1024) * 256 + tid) * 4;  // 4 elems/thread
    const int row = idx >> 10;                              // b*T + t
    const float m = (float)mask[row];
    float4 v = *(const float4*)(x + idx);
    ushort4 o;
    o.x = f2bf(v.x * m);
    o.y = f2bf(v.y * m);
    o.z = f2bf(v.z * m);
    o.w = f2bf(v.w * m);
    *(ushort4*)(xb + idx) = o;
  }
}

// ---------------------------------------------------------------- GEMM 128x128 (BK=64+swz)
// C[m][n] = sum_k A[m][k]*Bt[n][k]; 4 waves, one barrier-pair / 32 MFMAs.
// MODE: 0 = bf16 [m][n], 2 = bf16 V-transposed [(b*16+h)*64+u][t]
template <int MODE>
__device__ __forceinline__ void gemm64_body(const unsigned short* __restrict__ A,
                                            const unsigned short* __restrict__ Bt,
                                            void* __restrict__ Cout) {
  constexpr int Kd = 1024, Nd = 1024;
  __shared__ unsigned short la[128 * 64];  // [row][64k], swizzled contents, 16KB
  __shared__ unsigned short lb[128 * 64];
  const int tid = threadIdx.x;
  const int lane = tid & 63;
  const int w = tid >> 6;
  const int mb = blockIdx.y * 128, nb = blockIdx.x * 128;
  const int wm = (w >> 1) * 64, wn = (w & 1) * 64;
  const int lr = lane & 15, lg = lane >> 4;
  const int srow = tid >> 3;               // 0..31 (+i*32 per issue)
  const int scol = (tid & 7) * 8;
  const int sc = scol ^ ((srow & 7) << 3); // pre-swizzled SOURCE col
  const unsigned short* gA = A + (size_t)(mb + srow) * Kd + sc;
  const unsigned short* gB = Bt + (size_t)(nb + srow) * Kd + sc;
  unsigned short* lA = la + srow * 64 + scol;
  unsigned short* lB = lb + srow * 64 + scol;
  const int rsw = (lr & 7) << 3;           // read-side swizzle (shorts)

  f32x4 acc[4][4] = {};

  for (int kt = 0; kt < Kd; kt += 64) {
#pragma unroll
    for (int i = 0; i < 4; i++) {
      gld16(gA + kt + (size_t)(i * 32) * Kd, lA + i * 32 * 64);
      gld16(gB + kt + (size_t)(i * 32) * Kd, lB + i * 32 * 64);
    }
    __syncthreads();
#pragma unroll
    for (int ks = 0; ks < 2; ks++) {
      const int kc = (ks * 32 + lg * 8) ^ rsw;
      s16x8 af[4], bfr[4];
#pragma unroll
      for (int i = 0; i < 4; i++)
        af[i] = *(const s16x8*)(la + (wm + i * 16 + lr) * 64 + kc);
#pragma unroll
      for (int j = 0; j < 4; j++)
        bfr[j] = *(const s16x8*)(lb + (wn + j * 16 + lr) * 64 + kc);
#pragma unroll
      for (int i = 0; i < 4; i++)
#pragma unroll
        for (int j = 0; j < 4; j++)
          acc[i][j] = mfma16(af[i], bfr[j], acc[i][j]);
    }
    __syncthreads();
  }

#pragma unroll
  for (int i = 0; i < 4; i++)
#pragma unroll
    for (int j = 0; j < 4; j++) {
      const int col = nb + wn + j * 16 + lr;
      const int rowb = mb + wm + i * 16 + lg * 4;
      if (MODE == 0) {
        unsigned short* C = (unsigned short*)Cout;
#pragma unroll
        for (int r = 0; r < 4; r++) C[(size_t)(rowb + r) * Nd + col] = f2bf(acc[i][j][r]);
      } else {
        unsigned short* C = (unsigned short*)Cout;
        const size_t vrow = ((size_t)(rowb >> 11) * 16 + (col >> 6)) * 64 + (col & 63);
        ushort4 o;
#pragma unroll
        for (int r = 0; r < 4; r++) ((unsigned short*)&o)[r] = f2bf(acc[i][j][r]);
        *(ushort4*)(C + vrow * T_ + (rowb & 2047)) = o;
      }
    }
}

__global__ __launch_bounds__(256) void gemm_qkv(const unsigned short* __restrict__ A,
                                                const unsigned short* __restrict__ wq,
                                                const unsigned short* __restrict__ wk,
                                                const unsigned short* __restrict__ wv,
                                                unsigned short* __restrict__ cq,
                                                unsigned short* __restrict__ ck,
                                                unsigned short* __restrict__ vt) {
  if (blockIdx.z == 0) {
    gemm64_body<0>(A, wq, cq);
  } else if (blockIdx.z == 1) {
    gemm64_body<0>(A, wk, ck);
  } else {
    gemm64_body<2>(A, wv, vt);  // writes V directly transposed
  }
}

// ---------------------------------------------------------------- gemm_out: 128x64 tile
// 512 blocks = 2 blocks/CU: cross-block overlap of the barrier drain.
__global__ __launch_bounds__(256) void gemm_out(const unsigned short* __restrict__ A,
                                                const unsigned short* __restrict__ woT,
                                                float* __restrict__ C) {
  constexpr int Kd = 1024, Nd = 1024;
  __shared__ unsigned short la[128 * 64];  // A tile 128x64k, 16KB
  __shared__ unsigned short lb[64 * 64];   // B tile 64x64k, 8KB
  const int tid = threadIdx.x;
  const int lane = tid & 63;
  const int w = tid >> 6;
  const int mb = blockIdx.y * 128, nb = blockIdx.x * 64;
  const int wm = w * 32;                   // wave's 32 M-rows
  const int lr = lane & 15, lg = lane >> 4;
  const int srow = tid >> 3;               // 0..31
  const int scol = (tid & 7) * 8;
  const int sc = scol ^ ((srow & 7) << 3);
  const unsigned short* gA = A + (size_t)(mb + srow) * Kd + sc;
  const unsigned short* gB = woT + (size_t)(nb + srow) * Kd + sc;
  unsigned short* lA = la + srow * 64 + scol;
  unsigned short* lB = lb + srow * 64 + scol;
  const int rsw = (lr & 7) << 3;

  f32x4 acc[2][4] = {};

  for (int kt = 0; kt < Kd; kt += 64) {
#pragma unroll
    for (int i = 0; i < 4; i++)
      gld16(gA + kt + (size_t)(i * 32) * Kd, lA + i * 32 * 64);
#pragma unroll
    for (int i = 0; i < 2; i++)
      gld16(gB + kt + (size_t)(i * 32) * Kd, lB + i * 32 * 64);
    __syncthreads();
#pragma unroll
    for (int ks = 0; ks < 2; ks++) {
      const int kc = (ks * 32 + lg * 8) ^ rsw;
      s16x8 af[2], bfr[4];
#pragma unroll
      for (int i = 0; i < 2; i++)
        af[i] = *(const s16x8*)(la + (wm + i * 16 + lr) * 64 + kc);
#pragma unroll
      for (int j = 0; j < 4; j++)
        bfr[j] = *(const s16x8*)(lb + (j * 16 + lr) * 64 + kc);
#pragma unroll
      for (int i = 0; i < 2; i++)
#pragma unroll
        for (int j = 0; j < 4; j++)
          acc[i][j] = mfma16(af[i], bfr[j], acc[i][j]);
    }
    __syncthreads();
  }

#pragma unroll
  for (int i = 0; i < 2; i++)
#pragma unroll
    for (int j = 0; j < 4; j++) {
      const int col = nb + j * 16 + lr;
      const int rowb = mb + wm + i * 16 + lg * 4;
#pragma unroll
      for (int r = 0; r < 4; r++) C[(size_t)(rowb + r) * Nd + col] = acc[i][j][r];
    }
}

// ---------------------------------------------------------------- K3: flash attention v17
// (byte-identical to rounds 17-19/21 — the measured 73.7us floor for this structure)
__global__ __launch_bounds__(64) void attn17_kernel(const unsigned short* __restrict__ Q,
                                                    const unsigned short* __restrict__ K,
                                                    const unsigned short* __restrict__ Vt,
                                                    const int* __restrict__ mask,
                                                    unsigned short* __restrict__ att) {
  __shared__ unsigned short pbuf[32 * 64];  // P repack, XOR-swizzled, 4KB
  const int lane = threadIdx.x & 63;
  const int li = lane & 15, lg = lane >> 4;
  const int bh = blockIdx.x & 31;
  const int b = bh >> 4, h = bh & 15;
  const int pr = blockIdx.x >> 5;           // 0..31: pair index

  const float CS = 0.125f * 1.44269504089f;   // 1/sqrt(U) * log2(e)
  const float PB = 10000.0f * 1.44269504089f; // pad bias, log2 domain
  const float THR = 8.0f;                     // defer-max threshold (log2 domain)

  const unsigned short* Kb = K + (size_t)(b * T_) * 1024 + h * 64;
  const unsigned short* Vtb = Vt + (size_t)bh * 64 * T_;
  const int* mk = mask + b * T_;

  const int xr = (li & 3) << 5;
  char* pbb = (char*)pbuf;

  for (int g = 0; g < 2; g++) {
    const int qg = g == 0 ? (63 - pr) : pr;
    const int q0 = qg * 32;

    s16x8 qf[2][2];
#pragma unroll
    for (int f = 0; f < 2; f++) {
      const unsigned short* qrow = Q + ((size_t)(b * T_) + q0 + f * 16 + li) * 1024 + h * 64;
      qf[f][0] = *(const s16x8*)(qrow + lg * 8);
      qf[f][1] = *(const s16x8*)(qrow + 32 + lg * 8);
    }

    const int iq0 = q0 + li, iq1 = q0 + 16 + li;

    float mrun[2] = {-1e30f, -1e30f};
    f32x4 lp[2] = {};              // vectorized per-lane partial row-sums
    f32x4 acc[4][2] = {};          // [ufrag][ifrag]
    s16x8 vf[4][2];                // V fragments, consumed within each phase

    const int ntiles = (q0 + 95) >> 6;  // ceil((q0+32)/64)

    auto loadK = [&](s16x8 (&dst)[4][2], int jb) {
#pragma unroll
      for (int jf = 0; jf < 4; jf++) {
        const unsigned short* kr = Kb + (size_t)(jb + jf * 16 + li) * 1024 + lg * 8;
        dst[jf][0] = *(const s16x8*)kr;
        dst[jf][1] = *(const s16x8*)(kr + 32);
      }
    };
    auto loadM = [&](int4 (&dst)[4], int jb) {
#pragma unroll
      for (int jf = 0; jf < 4; jf++)
        dst[jf] = *(const int4*)(mk + jb + jf * 16 + lg * 4);
    };
    auto loadV = [&](int jb) {
#pragma unroll
      for (int uf = 0; uf < 4; uf++) {
        const unsigned short* vr = Vtb + (size_t)(uf * 16 + li) * T_ + jb + lg * 8;
        vf[uf][0] = *(const s16x8*)vr;
        vf[uf][1] = *(const s16x8*)(vr + 32);
      }
    };
    auto qk = [&](f32x4 (&s)[4][2], s16x8 (&kc)[4][2]) {
      __builtin_amdgcn_s_setprio(1);
#pragma unroll
      for (int jf = 0; jf < 4; jf++) {
        f32x4 z = {};
        s[jf][0] = mfma16(kc[jf][0], qf[0][0], z);
        s[jf][0] = mfma16(kc[jf][1], qf[0][1], s[jf][0]);
        f32x4 z2 = {};
        s[jf][1] = mfma16(kc[jf][0], qf[1][0], z2);
        s[jf][1] = mfma16(kc[jf][1], qf[1][1], s[jf][1]);
      }
      __builtin_amdgcn_s_setprio(0);
    };
    auto smw = [&](f32x4 (&s)[4][2], int4 (&mv)[4], int jb) {
      const bool diag = (jb + 64 > q0);  // wave-uniform
      const int band = (mv[0].x & mv[0].y & mv[0].z & mv[0].w) &
                       (mv[1].x & mv[1].y & mv[1].z & mv[1].w) &
                       (mv[2].x & mv[2].y & mv[2].z & mv[2].w) &
                       (mv[3].x & mv[3].y & mv[3].z & mv[3].w);
      const bool noBias = __all(band != 0);
#pragma unroll
      for (int f = 0; f < 2; f++) {
        const int iq = f ? iq1 : iq0;
        f32x4 pv4 = {-3e38f, -3e38f, -3e38f, -3e38f};
        if (noBias) {
#pragma unroll
          for (int jf = 0; jf < 4; jf++) {
            f32x4 zz = s[jf][f] * CS;
            if (diag) {
#pragma unroll
              for (int r = 0; r < 4; r++)
                if (jb + jf * 16 + lg * 4 + r > iq) zz[r] = -1e30f;
            }
            s[jf][f] = zz;
            pv4 = __builtin_elementwise_max(pv4, zz);
          }
        } else {
#pragma unroll
          for (int jf = 0; jf < 4; jf++) {
            f32x4 zz;
#pragma unroll
            for (int r = 0; r < 4; r++) {
              float z = fmaf(s[jf][f][r], CS, ((&mv[jf].x)[r] ? 0.f : -PB));
              if (diag && (jb + jf * 16 + lg * 4 + r > iq)) z = -1e30f;
              zz[r] = z;
            }
            s[jf][f] = zz;
            pv4 = __builtin_elementwise_max(pv4, zz);
          }
        }
        const float pmax = fmaxf(fmaxf(pv4[0], pv4[1]), fmaxf(pv4[2], pv4[3]));
        if (!__all(pmax <= mrun[f] + THR)) {  // defer-max: rare after tile 0
          float rmax = fmaxf(pmax, __shfl_xor(pmax, 16));
          rmax = fmaxf(rmax, __shfl_xor(rmax, 32));
          const float mnew = fmaxf(mrun[f], rmax);
          const float al = exp2_hw(mrun[f] - mnew);
          lp[f] *= al;
#pragma unroll
          for (int uf = 0; uf < 4; uf++) acc[uf][f] *= al;
          mrun[f] = mnew;
        }
        const float mm = mrun[f];
#pragma unroll
        for (int jf = 0; jf < 4; jf++) {
          f32x4 p;
#pragma unroll
          for (int r = 0; r < 4; r++) p[r] = exp2_hw(s[jf][f][r] - mm);  // bounded 2^THR
          lp[f] += p;
          uint2 w2;
          w2.x = cvtpk_bf16(p[0], p[1]);
          w2.y = cvtpk_bf16(p[2], p[3]);
          const int wb = (((f * 16 + li) * 64 + jf * 16 + lg * 4) * 2) ^ xr;
          *(uint2*)(pbb + wb) = w2;
        }
      }
    };
    auto pv = [&]() {
      s16x8 pfrag[2][2];
#pragma unroll
      for (int f = 0; f < 2; f++)
#pragma unroll
        for (int hh = 0; hh < 2; hh++) {
          const int rd = (((f * 16 + li) * 64 + hh * 32 + lg * 8) * 2) ^ xr;
          pfrag[f][hh] = *(const s16x8*)(pbb + rd);
        }
      __builtin_amdgcn_s_setprio(1);
#pragma unroll
      for (int uf = 0; uf < 4; uf++)
#pragma unroll
        for (int f = 0; f < 2; f++) {
          acc[uf][f] = mfma16(vf[uf][0], pfrag[f][0], acc[uf][f]);
          acc[uf][f] = mfma16(vf[uf][1], pfrag[f][1], acc[uf][f]);
        }
      __builtin_amdgcn_s_setprio(0);
    };

    s16x8 kA[4][2], kB[4][2];
    f32x4 sA[4][2], sB[4][2];
    int4 mA[4], mB[4];

    loadK(kA, 0);
    loadM(mA, 0);
    qk(sA, kA);
    if (ntiles > 1) {
      loadK(kB, 64);
      loadM(mB, 64);
    }

    int t = 0;
    while (true) {
      {
        const int jb = t * 64;
        loadV(jb);                 // flies under softmax
        smw(sA, mA, jb);           // pbuf writes
        if (t + 1 < ntiles) qk(sB, kB);          // hides pbuf write->read
        if (t + 2 < ntiles) {
          loadK(kA, (t + 2) * 64);
          loadM(mA, (t + 2) * 64);
        }
        pv();                      // pbuf reads + PV MFMAs
      }
      if (t + 1 >= ntiles) break;
      {
        const int jb = (t + 1) * 64;
        loadV(jb);
        smw(sB, mB, jb);
        if (t + 2 < ntiles) qk(sA, kA);
        if (t + 3 < ntiles) {
          loadK(kB, (t + 3) * 64);
          loadM(mB, (t + 3) * 64);
        }
        pv();
      }
      t += 2;
      if (t >= ntiles) break;
    }

    // ---- epilogue: reduce lp once, then normalize + store
#pragma unroll
    for (int f = 0; f < 2; f++) {
      float l = (lp[f][0] + lp[f][1]) + (lp[f][2] + lp[f][3]);
      l += __shfl_xor(l, 16);
      l += __shfl_xor(l, 32);
      const float inv = 1.0f / l;
      unsigned short* arow = att + ((size_t)(b * T_) + q0 + f * 16 + li) * 1024 + h * 64;
#pragma unroll
      for (int uf = 0; uf < 4; uf++) {
        ushort4 o;
#pragma unroll
        for (int r = 0; r < 4; r++)
          ((unsigned short*)&o)[r] = __builtin_bit_cast(unsigned short, (__bf16)(acc[uf][f][r] * inv));
        *(ushort4*)(arow + uf * 16 + lg * 4) = o;
      }
    }
  }
}

// ----------------------------------------------------------------
extern "C" void kernel_launch(void* const* d_in, const int* in_sizes, int n_in,
                              void* d_out, int out_size, void* d_ws, size_t ws_size,
                              hipStream_t stream) {
  const float* x = (const float*)d_in[0];
  const int* mask = (const int*)d_in[1];
  const float* Wq = (const float*)d_in[2];
  const float* Wk = (const float*)d_in[3];
  const float* Wv = (const float*)d_in[4];
  const float* Wo = (const float*)d_in[5];

  const size_t MB = 1u << 20;
  char* ws = (char*)d_ws;
  unsigned short* wqT = (unsigned short*)(ws + 0 * MB);
  unsigned short* wkT = (unsigned short*)(ws + 2 * MB);
  unsigned short* wvT = (unsigned short*)(ws + 4 * MB);
  unsigned short* woT = (unsigned short*)(ws + 6 * MB);
  unsigned short* xb  = (unsigned short*)(ws + 8 * MB);   // 8MB; dead after gemm_qkv
  unsigned short* qb  = (unsigned short*)(ws + 16 * MB);  // 8MB
  unsigned short* kb  = (unsigned short*)(ws + 24 * MB);  // 8MB
  unsigned short* vt  = (unsigned short*)(ws + 32 * MB);  // 8MB, written transposed by gemm_qkv
  unsigned short* att = xb;                               // reuse xb slot (dead by attn time)
  (void)ws_size; (void)in_sizes; (void)n_in; (void)out_size;

  prep_kernel<<<dim3(5120), 256, 0, stream>>>(x, mask, Wq, Wk, Wv, Wo,
                                              wqT, wkT, wvT, woT, xb);
  gemm_qkv<<<dim3(8, 32, 3), 256, 0, stream>>>(xb, wqT, wkT, wvT, qb, kb, vt);
  attn17_kernel<<<dim3(1024), 64, 0, stream>>>(qb, kb, vt, mask, att);
  gemm_out<<<dim3(16, 32), 256, 0, stream>>>(att, woT, (float*)d_out);
}